// Round 2
// baseline (8361.706 us; speedup 1.0000x reference)
//
#include <hip/hip_runtime.h>
#include <hip/hip_bf16.h>

// Problem constants
#define T_STEPS 64
#define BATCH   1024
#define HID     512
#define GATES   2048          // 4*H
#define KDIM    1024          // IN + H
#define BH      (BATCH*HID)   // 524288
#define THB     (T_STEPS*BATCH*HID)
#define NGRP    8             // m-groups (128 rows each)
#define GRPSZ   32            // j-blocks per group

typedef __attribute__((ext_vector_type(4))) float f32x4;
typedef __attribute__((ext_vector_type(8))) short short8;

__device__ __forceinline__ float sigmoidf_(float x) { return 1.f / (1.f + __expf(-x)); }

// ---- device-scope group flags (per-XCD L2s are NOT coherent: fence + agent atomics) ----
__device__ __forceinline__ void sig_flag(int* f) {
    __syncthreads();                       // all waves' stores drained (vmcnt(0) at barrier)
    if (threadIdx.x == 0) {
        __threadfence();                   // release: L2 writeback, device visibility
        __hip_atomic_fetch_add(f, 1, __ATOMIC_RELEASE, __HIP_MEMORY_SCOPE_AGENT);
    }
}
__device__ __forceinline__ void wait_flag(int* f, int target) {
    if (threadIdx.x == 0) {
        while (__hip_atomic_load(f, __ATOMIC_RELAXED, __HIP_MEMORY_SCOPE_AGENT) < target)
            __builtin_amdgcn_s_sleep(8);
        __threadfence();                   // acquire: invalidate stale cache lines
    }
    __syncthreads();
}

// ---------------- weight packing: [w_ih | w_hh] -> bf16 [2048][1024], bias sum ----------------
__global__ void pack_weights(const float* __restrict__ wih0, const float* __restrict__ whh0,
                             const float* __restrict__ wih1, const float* __restrict__ whh1,
                             const float* __restrict__ bih0, const float* __restrict__ bhh0,
                             const float* __restrict__ bih1, const float* __restrict__ bhh1,
                             __hip_bfloat16* __restrict__ w0p, __hip_bfloat16* __restrict__ w1p,
                             float* __restrict__ b0, float* __restrict__ b1)
{
    int idx = blockIdx.x * 256 + threadIdx.x;   // over 2048*1024
    int n = idx >> 10, k = idx & 1023;
    float v0 = (k < 512) ? wih0[n * 512 + k] : whh0[n * 512 + (k - 512)];
    float v1 = (k < 512) ? wih1[n * 512 + k] : whh1[n * 512 + (k - 512)];
    w0p[idx] = __float2bfloat16(v0);
    w1p[idx] = __float2bfloat16(v1);
    if (idx < GATES) {
        b0[idx] = bih0[idx] + bhh0[idx];
        b1[idx] = bih1[idx] + bhh1[idx];
    }
}

// ---- 128x64 GEMM tile over K=1024 (verbatim core from the verified per-step kernel) ----
__device__ __forceinline__ void gemm_tile(const short* __restrict__ Ag, const short* __restrict__ Wg,
                                          short* As, short* Ws,
                                          int tid, int wave, int lr, int lq,
                                          int m0, int j0, f32x4 acc[2][4])
{
    for (int k0 = 0; k0 < KDIM; k0 += 64) {
#pragma unroll
        for (int i = 0; i < 4; ++i) {            // A: 128 m-rows x 64 k
            int c  = tid + i * 256;
            int r  = c >> 3;
            int kk = (c & 7) * 8;
            *(short8*)&As[r * 72 + kk] = *(const short8*)&Ag[(size_t)(m0 + r) * KDIM + k0 + kk];
        }
#pragma unroll
        for (int i = 0; i < 2; ++i) {            // W: 64 gate-rows (4 gates x 16 j)
            int c  = tid + i * 256;
            int r  = c >> 3;
            int kk = (c & 7) * 8;
            int grow = (r >> 4) * 512 + j0 + (r & 15);
            *(short8*)&Ws[r * 72 + kk] = *(const short8*)&Wg[(size_t)grow * KDIM + k0 + kk];
        }
        __syncthreads();
#pragma unroll
        for (int kk = 0; kk < 64; kk += 32) {
            short8 a0 = *(const short8*)&As[(wave * 16 + lr) * 72 + kk + lq * 8];
            short8 a1 = *(const short8*)&As[(64 + wave * 16 + lr) * 72 + kk + lq * 8];
#pragma unroll
            for (int g = 0; g < 4; ++g) {
                short8 w = *(const short8*)&Ws[(g * 16 + lr) * 72 + kk + lq * 8];
                acc[0][g] = __builtin_amdgcn_mfma_f32_16x16x32_bf16(a0, w, acc[0][g], 0, 0, 0);
                acc[1][g] = __builtin_amdgcn_mfma_f32_16x16x32_bf16(a1, w, acc[1][g], 0, 0, 0);
            }
        }
        __syncthreads();
    }
}

// =====================================================================================
// Persistent LSTM scan, plain launch, 256 blocks. Group = 32 j-blocks sharing a 128-row
// m-slice; each block runs BOTH layers for all 64 steps. All flag deps are group-local:
//   fX[t][mg]: step-t inputs ready (xh0 full + xh1 h1-half), signaled end of step t-1
//   fY[t][mg]: h0-half of xh1 buf(t&1) written, signaled after L0 GEMM+cell
// Buffers: xh0 single (rewrite guarded by fY wait = all group blocks done reading),
//          xh1 double (h1-prep written to opposite parity of the buffer being read).
// c-state in registers (16 floats/thread); h-state only inside xh buffers.
// =====================================================================================
__global__ __launch_bounds__(256, 2) void lstm_scan(
    const float* __restrict__ latent, const float* __restrict__ h_t, const float* __restrict__ c_t,
    const int* __restrict__ reset_mask, const int* __restrict__ clear_mask,
    const float* __restrict__ noise_std, const float* __restrict__ noise,
    const __hip_bfloat16* __restrict__ w0p, const __hip_bfloat16* __restrict__ w1p,
    const float* __restrict__ b0, const float* __restrict__ b1,
    __hip_bfloat16* __restrict__ xh0,   // [1024][1024] bf16
    __hip_bfloat16* __restrict__ xh1,   // 2 buffers of [1024][1024] bf16
    int* __restrict__ flags, float* __restrict__ out)
{
    __shared__ short As[128 * 72];
    __shared__ short Ws[64 * 72];
    const int tid  = threadIdx.x;
    const int lane = tid & 63;
    const int wave = tid >> 6;
    const int lr   = lane & 15;
    const int lq   = lane >> 4;
    const int b    = blockIdx.x;
    const int xcd  = b & 7;
    const int seq  = b >> 3;            // 0..31
    const int jb   = xcd * 4 + (seq >> 3);   // 0..31: XCD keeps 4 jb's W slice (~1MB) L2-resident
    const int mg   = seq & 7;           // 0..7
    const int m0   = mg * 128;
    const int j0   = jb * 16;
    const int j    = j0 + lr;

    int* fX = flags;                    // [65][NGRP]
    int* fY = flags + 65 * NGRP;        // [64][NGRP]

    const float bi0 = b0[j],        bf0 = b0[512 + j];
    const float bg0 = b0[1024 + j], bo0 = b0[1536 + j];
    const float bi1 = b1[j],        bf1 = b1[512 + j];
    const float bg1 = b1[1024 + j], bo1 = b1[1536 + j];

    float cs0[2][4], cs1[2][4];

    // ---------------- init: t=0 prep for both layers ----------------
#pragma unroll
    for (int mt = 0; mt < 2; ++mt)
#pragma unroll
    for (int r = 0; r < 4; ++r) {
        int m   = m0 + mt * 64 + wave * 16 + lq * 4 + r;
        int idx = m * HID + j;
        bool msk = (reset_mask[m * T_STEPS] | clear_mask[m * T_STEPS]) != 0;
        float s  = noise_std[m * T_STEPS];
        float nv0 = noise[(size_t)m * HID + j] * s;                      // noise[0][0][m][j]
        float nv1 = noise[((size_t)BATCH + m) * HID + j] * s;            // noise[0][1][m][j]
        float h0p = (msk ? 0.f : h_t[idx]) + nv0;
        cs0[mt][r] = (msk ? 0.f : c_t[idx]) + nv0;
        float h1p = (msk ? 0.f : h_t[BH + idx]) + nv1;
        cs1[mt][r] = (msk ? 0.f : c_t[BH + idx]) + nv1;
        xh0[m * KDIM + j]       = __float2bfloat16(latent[idx]);
        xh0[m * KDIM + 512 + j] = __float2bfloat16(h0p);
        xh1[m * KDIM + 512 + j] = __float2bfloat16(h1p);                 // buf 0
    }
    sig_flag(&fX[mg]);

    for (int t = 0; t < T_STEPS; ++t) {
        wait_flag(&fX[t * NGRP + mg], GRPSZ);

        // ---- layer 0 GEMM + cell ----
        f32x4 acc[2][4];
#pragma unroll
        for (int mt = 0; mt < 2; ++mt)
#pragma unroll
        for (int g = 0; g < 4; ++g) acc[mt][g] = (f32x4){0.f, 0.f, 0.f, 0.f};
        gemm_tile((const short*)xh0, (const short*)w0p, As, Ws, tid, wave, lr, lq, m0, j0, acc);

        float hv0[2][4], cv0[2][4];
#pragma unroll
        for (int mt = 0; mt < 2; ++mt)
#pragma unroll
        for (int r = 0; r < 4; ++r) {
            float gi = acc[mt][0][r] + bi0, gf = acc[mt][1][r] + bf0;
            float gg = acc[mt][2][r] + bg0, go = acc[mt][3][r] + bo0;
            float cn = sigmoidf_(gf) * cs0[mt][r] + sigmoidf_(gi) * tanhf(gg);
            hv0[mt][r] = sigmoidf_(go) * tanhf(cn);
            cv0[mt][r] = cn;
        }

        __hip_bfloat16* xb = xh1 + (size_t)(t & 1) * BATCH * KDIM;
#pragma unroll
        for (int mt = 0; mt < 2; ++mt)
#pragma unroll
        for (int r = 0; r < 4; ++r) {
            int m = m0 + mt * 64 + wave * 16 + lq * 4 + r;
            xb[m * KDIM + j] = __float2bfloat16(hv0[mt][r]);
        }
        sig_flag(&fY[t * NGRP + mg]);
        wait_flag(&fY[t * NGRP + mg], GRPSZ);   // all h0 cols present; all done reading xh0

        if (t < T_STEPS - 1) {
            // prep layer-0 inputs for t+1 (xh0 is safe to overwrite now)
            int tn = t + 1;
#pragma unroll
            for (int mt = 0; mt < 2; ++mt)
#pragma unroll
            for (int r = 0; r < 4; ++r) {
                int m   = m0 + mt * 64 + wave * 16 + lq * 4 + r;
                int idx = m * HID + j;
                bool msk = (reset_mask[m * T_STEPS + tn] | clear_mask[m * T_STEPS + tn]) != 0;
                float nv = noise[((size_t)(tn * 2) * BATCH + m) * HID + j] * noise_std[m * T_STEPS + tn];
                float h0p = (msk ? 0.f : hv0[mt][r]) + nv;
                cs0[mt][r] = (msk ? 0.f : cv0[mt][r]) + nv;
                xh0[m * KDIM + j]       = __float2bfloat16(latent[(size_t)tn * BH + idx]);
                xh0[m * KDIM + 512 + j] = __float2bfloat16(h0p);
            }
        } else {
#pragma unroll
            for (int mt = 0; mt < 2; ++mt)
#pragma unroll
            for (int r = 0; r < 4; ++r) {
                int m   = m0 + mt * 64 + wave * 16 + lq * 4 + r;
                int idx = m * HID + j;
                out[THB + idx]          = hv0[mt][r];
                out[THB + 2 * BH + idx] = cv0[mt][r];
            }
        }

        // ---- layer 1 GEMM + cell ----
#pragma unroll
        for (int mt = 0; mt < 2; ++mt)
#pragma unroll
        for (int g = 0; g < 4; ++g) acc[mt][g] = (f32x4){0.f, 0.f, 0.f, 0.f};
        gemm_tile((const short*)xb, (const short*)w1p, As, Ws, tid, wave, lr, lq, m0, j0, acc);

        float hv1[2][4], cv1[2][4];
#pragma unroll
        for (int mt = 0; mt < 2; ++mt)
#pragma unroll
        for (int r = 0; r < 4; ++r) {
            float gi = acc[mt][0][r] + bi1, gf = acc[mt][1][r] + bf1;
            float gg = acc[mt][2][r] + bg1, go = acc[mt][3][r] + bo1;
            float cn = sigmoidf_(gf) * cs1[mt][r] + sigmoidf_(gi) * tanhf(gg);
            hv1[mt][r] = sigmoidf_(go) * tanhf(cn);
            cv1[mt][r] = cn;
        }

#pragma unroll
        for (int mt = 0; mt < 2; ++mt)
#pragma unroll
        for (int r = 0; r < 4; ++r) {
            int m   = m0 + mt * 64 + wave * 16 + lq * 4 + r;
            out[(size_t)t * BH + m * HID + j] = hv1[mt][r];
        }

        if (t < T_STEPS - 1) {
            int tn = t + 1;
            __hip_bfloat16* xn = xh1 + (size_t)(tn & 1) * BATCH * KDIM;  // opposite parity: no race
#pragma unroll
            for (int mt = 0; mt < 2; ++mt)
#pragma unroll
            for (int r = 0; r < 4; ++r) {
                int m = m0 + mt * 64 + wave * 16 + lq * 4 + r;
                bool msk = (reset_mask[m * T_STEPS + tn] | clear_mask[m * T_STEPS + tn]) != 0;
                float nv = noise[((size_t)(tn * 2 + 1) * BATCH + m) * HID + j] * noise_std[m * T_STEPS + tn];
                float h1p = (msk ? 0.f : hv1[mt][r]) + nv;
                cs1[mt][r] = (msk ? 0.f : cv1[mt][r]) + nv;
                xn[m * KDIM + 512 + j] = __float2bfloat16(h1p);
            }
            sig_flag(&fX[tn * NGRP + mg]);
        } else {
#pragma unroll
            for (int mt = 0; mt < 2; ++mt)
#pragma unroll
            for (int r = 0; r < 4; ++r) {
                int m   = m0 + mt * 64 + wave * 16 + lq * 4 + r;
                int idx = m * HID + j;
                out[THB + BH + idx]     = hv1[mt][r];
                out[THB + 3 * BH + idx] = cv1[mt][r];
            }
        }
    }
}

extern "C" void kernel_launch(void* const* d_in, const int* in_sizes, int n_in,
                              void* d_out, int out_size, void* d_ws, size_t ws_size,
                              hipStream_t stream)
{
    const float* latent     = (const float*)d_in[0];
    const float* h_t        = (const float*)d_in[1];
    const float* c_t        = (const float*)d_in[2];
    const int*   reset_mask = (const int*)d_in[3];   // (1,B,T,1) flat b*T+t
    const int*   clear_mask = (const int*)d_in[4];   // (B,T)     flat b*T+t
    const float* noise_std  = (const float*)d_in[5]; // (B,T)     flat b*T+t
    const float* noise      = (const float*)d_in[6]; // (T,L,B,H)
    const float* wih0 = (const float*)d_in[7];
    const float* whh0 = (const float*)d_in[8];
    const float* bih0 = (const float*)d_in[9];
    const float* bhh0 = (const float*)d_in[10];
    const float* wih1 = (const float*)d_in[11];
    const float* whh1 = (const float*)d_in[12];
    const float* bih1 = (const float*)d_in[13];
    const float* bhh1 = (const float*)d_in[14];
    float* out = (float*)d_out;

    char* ws = (char*)d_ws;
    size_t off = 0;
    auto alloc = [&](size_t bytes) -> void* {
        void* p = ws + off;
        off += (bytes + 255) & ~(size_t)255;
        return p;
    };
    __hip_bfloat16* w0p = (__hip_bfloat16*)alloc((size_t)GATES * KDIM * 2);
    __hip_bfloat16* w1p = (__hip_bfloat16*)alloc((size_t)GATES * KDIM * 2);
    float* b0 = (float*)alloc(GATES * 4);
    float* b1 = (float*)alloc(GATES * 4);
    __hip_bfloat16* xh0 = (__hip_bfloat16*)alloc((size_t)BATCH * KDIM * 2);
    __hip_bfloat16* xh1 = (__hip_bfloat16*)alloc((size_t)2 * BATCH * KDIM * 2);  // double-buffered
    int* flags = (int*)alloc((size_t)2 * 65 * NGRP * sizeof(int));

    hipMemsetAsync(flags, 0, (size_t)2 * 65 * NGRP * sizeof(int), stream);

    pack_weights<<<(GATES * KDIM) / 256, 256, 0, stream>>>(
        wih0, whh0, wih1, whh1, bih0, bhh0, bih1, bhh1, w0p, w1p, b0, b1);

    lstm_scan<<<256, 256, 0, stream>>>(
        latent, h_t, c_t, reset_mask, clear_mask, noise_std, noise,
        w0p, w1p, b0, b1, xh0, xh1, flags, out);
}

// Round 3
// 4306.964 us; speedup vs baseline: 1.9414x; 1.9414x over previous
//
#include <hip/hip_runtime.h>
#include <hip/hip_bf16.h>

// Problem constants
#define T_STEPS 64
#define BATCH   1024
#define HID     512
#define GATES   2048          // 4*H
#define KDIM    1024          // IN + H
#define BH      (BATCH*HID)   // 524288
#define THB     (T_STEPS*BATCH*HID)
#define NMG     16            // m-groups (64 rows each)
#define NJB     32            // j-blocks per group
#define BK      128           // k-chunk
#define LDA     136           // BK + 8 shorts pad (2-way-free banks)

typedef __attribute__((ext_vector_type(4))) float f32x4;
typedef __attribute__((ext_vector_type(8))) short short8;

__device__ __forceinline__ float sigmoidf_(float x) { return 1.f / (1.f + __expf(-x)); }

__device__ __forceinline__ unsigned short bf16b(float x) {
    __hip_bfloat16 b = __float2bfloat16(x);
    return *reinterpret_cast<unsigned short*>(&b);
}

// =====================================================================================
// Fence-free cross-block coherence (MI355X per-XCD L2s are NOT coherent):
//  - ALL cross-block data (h0 / h0prep / h1prep) moves via RELAXED AGENT-scope atomics,
//    which bypass L1/L2 and operate at the device coherence point. No __threadfence
//    (buffer_wbl2 / buffer_inv storms killed the previous version: 8361us, MfmaUtil 2.7%).
//  - Release ordering: __syncthreads() drains vmcnt(0) (stores acked at coherence point)
//    before thread0 writes the per-block arrival slot. Acquire ordering: consumers spin
//    on the 32 slots (agent loads, uncached), then __syncthreads() = compiler barrier.
//  - Per-slot arrival stores (no atomicAdd RMW contention).
//  - Groups = contiguous 32-block ranges, fully independent -> no deadlock under any
//    scheduling; no dependence on blockIdx->XCD mapping for correctness.
// =====================================================================================
__device__ __forceinline__ void sig_slot(unsigned* slot) {
    __syncthreads();                       // all block stores acked (vmcnt(0) before barrier)
    if (threadIdx.x == 0)
        __hip_atomic_store(slot, 1u, __ATOMIC_RELAXED, __HIP_MEMORY_SCOPE_AGENT);
}
__device__ __forceinline__ void wait_slots(unsigned* slots) {
    unsigned* p = slots + (threadIdx.x & 31);
    for (;;) {
        unsigned v = __hip_atomic_load(p, __ATOMIC_RELAXED, __HIP_MEMORY_SCOPE_AGENT);
        if (__all(v != 0)) break;
        __builtin_amdgcn_s_sleep(4);
    }
    __syncthreads();                       // joins waves + compiler memory barrier
}

// packed bf16 pair store (even lane stores {own j, partner j+1}) at agent scope
__device__ __forceinline__ void store_pair(__hip_bfloat16* base, int m, int j, float v, int lane) {
    float o = __shfl_xor(v, 1);
    if (!(lane & 1)) {
        unsigned pk = (unsigned)bf16b(v) | ((unsigned)bf16b(o) << 16);
        __hip_atomic_store((unsigned*)(base + (size_t)m * HID + j), pk,
                           __ATOMIC_RELAXED, __HIP_MEMORY_SCOPE_AGENT);
    }
}

// ---------------- weight packing: [w_ih | w_hh] -> bf16 [2048][1024], bias sum ----------------
__global__ void pack_weights(const float* __restrict__ wih0, const float* __restrict__ whh0,
                             const float* __restrict__ wih1, const float* __restrict__ whh1,
                             const float* __restrict__ bih0, const float* __restrict__ bhh0,
                             const float* __restrict__ bih1, const float* __restrict__ bhh1,
                             __hip_bfloat16* __restrict__ w0p, __hip_bfloat16* __restrict__ w1p,
                             float* __restrict__ b0, float* __restrict__ b1)
{
    int idx = blockIdx.x * 256 + threadIdx.x;   // over 2048*1024
    int n = idx >> 10, k = idx & 1023;
    float v0 = (k < 512) ? wih0[n * 512 + k] : whh0[n * 512 + (k - 512)];
    float v1 = (k < 512) ? wih1[n * 512 + k] : whh1[n * 512 + (k - 512)];
    w0p[idx] = __float2bfloat16(v0);
    w1p[idx] = __float2bfloat16(v1);
    if (idx < GATES) {
        b0[idx] = bih0[idx] + bhh0[idx];
        b1[idx] = bih1[idx] + bhh1[idx];
    }
}

// =====================================================================================
// Persistent LSTM scan: 512 blocks (2/CU), tile 64m x 64n (4 gates x 16 j), BK=128.
// Group = blocks [mg*32, mg*32+32): all 32 j-blocks of one 64-row m-slice; each block
// runs BOTH layers all 64 steps. Flags (per t, per group, 32 slots):
//   fX[t]: step-t inputs ready (h0prep[t&1], h1prep[t&1]) — signaled end of step t-1
//   fY[t]: h0[t] complete — signaled after L0 GEMM+cell
// h0 single-buffered (overwrite at t+1 guarded by fX[t+1] = everyone finished step t);
// h0p/h1p double-buffered by t&1. c-state in registers (8 floats/thread).
// =====================================================================================
__global__ __launch_bounds__(256, 2) void lstm_scan(
    const float* __restrict__ latent, const float* __restrict__ h_t, const float* __restrict__ c_t,
    const int* __restrict__ reset_mask, const int* __restrict__ clear_mask,
    const float* __restrict__ noise_std, const float* __restrict__ noise,
    const __hip_bfloat16* __restrict__ w0p, const __hip_bfloat16* __restrict__ w1p,
    const float* __restrict__ b0, const float* __restrict__ b1,
    __hip_bfloat16* h0p,   // [2][1024][512] bf16
    __hip_bfloat16* h1p,   // [2][1024][512] bf16
    __hip_bfloat16* h0,    // [1024][512] bf16
    unsigned* flags, float* __restrict__ out)
{
    __shared__ short As[64 * LDA];
    __shared__ short Ws[64 * LDA];
    const int tid  = threadIdx.x;
    const int lane = tid & 63;
    const int wave = tid >> 6;
    const int lr   = lane & 15;
    const int lq   = lane >> 4;
    const int b    = blockIdx.x;
    const int mg   = b >> 5;            // contiguous group -> co-residency per group
    const int jb   = b & 31;            // b%8 spans 4 jb per XCD -> 1MB W slice L2-hot
    const int m0   = mg * 64;
    const int j0   = jb * 16;
    const int j    = j0 + lr;

    unsigned* fX = flags;                              // [64][NMG][NJB]
    unsigned* fY = flags + (size_t)T_STEPS * NMG * NJB;

    const float bi0 = b0[j],        bf0 = b0[512 + j];
    const float bg0 = b0[1024 + j], bo0 = b0[1536 + j];
    const float bi1 = b1[j],        bf1 = b1[512 + j];
    const float bg1 = b1[1024 + j], bo1 = b1[1536 + j];

    float cs0[4], cs1[4];

    // ---------------- init: t=0 prep for both layers ----------------
#pragma unroll
    for (int r = 0; r < 4; ++r) {
        int m   = m0 + wave * 16 + lq * 4 + r;
        int idx = m * HID + j;
        bool msk = (reset_mask[m * T_STEPS] | clear_mask[m * T_STEPS]) != 0;
        float s  = noise_std[m * T_STEPS];
        float nv0 = noise[(size_t)m * HID + j] * s;             // noise[0][0][m][j]
        float nv1 = noise[((size_t)BATCH + m) * HID + j] * s;   // noise[0][1][m][j]
        float hp0 = (msk ? 0.f : h_t[idx]) + nv0;
        cs0[r] = (msk ? 0.f : c_t[idx]) + nv0;
        float hp1 = (msk ? 0.f : h_t[BH + idx]) + nv1;
        cs1[r] = (msk ? 0.f : c_t[BH + idx]) + nv1;
        store_pair(h0p, m, j, hp0, lane);                       // parity 0
        store_pair(h1p, m, j, hp1, lane);                       // parity 0
    }
    sig_slot(&fX[((size_t)0 * NMG + mg) * NJB + jb]);

    for (int t = 0; t < T_STEPS; ++t) {
        const int p = t & 1;
        wait_slots(&fX[((size_t)t * NMG + mg) * NJB]);

        // ---- layer 0 GEMM: A = [latent_t(f32->bf16) | h0prep[p]] ----
        f32x4 acc[4];
#pragma unroll
        for (int g = 0; g < 4; ++g) acc[g] = (f32x4){0.f, 0.f, 0.f, 0.f};
#pragma unroll
        for (int k0 = 0; k0 < KDIM; k0 += BK) {
            if (k0 < HID) {
#pragma unroll
                for (int i = 0; i < 4; ++i) {
                    int c = tid + i * 256;
                    int r = c >> 4;
                    int kk = (c & 15) * 8;
                    const float* src = &latent[((size_t)t * BATCH + m0 + r) * HID + k0 + kk];
                    f32x4 v0 = *(const f32x4*)src;
                    f32x4 v1 = *(const f32x4*)(src + 4);
                    short8 s;
                    s[0] = (short)bf16b(v0[0]); s[1] = (short)bf16b(v0[1]);
                    s[2] = (short)bf16b(v0[2]); s[3] = (short)bf16b(v0[3]);
                    s[4] = (short)bf16b(v1[0]); s[5] = (short)bf16b(v1[1]);
                    s[6] = (short)bf16b(v1[2]); s[7] = (short)bf16b(v1[3]);
                    *(short8*)&As[r * LDA + kk] = s;
                }
            } else {
                unsigned long long va[8];
#pragma unroll
                for (int i = 0; i < 8; ++i) {
                    int c = tid + i * 256;
                    int r = c >> 5;
                    int sc = (c & 31) * 4;
                    va[i] = __hip_atomic_load(
                        (unsigned long long*)(h0p + (size_t)p * BH + (size_t)(m0 + r) * HID + (k0 - HID) + sc),
                        __ATOMIC_RELAXED, __HIP_MEMORY_SCOPE_AGENT);
                }
#pragma unroll
                for (int i = 0; i < 8; ++i) {
                    int c = tid + i * 256;
                    int r = c >> 5;
                    int sc = (c & 31) * 4;
                    *(unsigned long long*)&As[r * LDA + sc] = va[i];
                }
            }
#pragma unroll
            for (int i = 0; i < 4; ++i) {
                int c = tid + i * 256;
                int r = c >> 4;
                int kk = (c & 15) * 8;
                int grow = (r >> 4) * 512 + j0 + (r & 15);
                *(short8*)&Ws[r * LDA + kk] = *(const short8*)&((const short*)w0p)[(size_t)grow * KDIM + k0 + kk];
            }
            __syncthreads();
#pragma unroll
            for (int kk = 0; kk < BK; kk += 32) {
                short8 a = *(const short8*)&As[(wave * 16 + lr) * LDA + kk + lq * 8];
#pragma unroll
                for (int g = 0; g < 4; ++g) {
                    short8 w = *(const short8*)&Ws[(g * 16 + lr) * LDA + kk + lq * 8];
                    acc[g] = __builtin_amdgcn_mfma_f32_16x16x32_bf16(a, w, acc[g], 0, 0, 0);
                }
            }
            __syncthreads();
        }

        // ---- cell 0 + h0 handoff + t+1 layer-0 prep ----
        float hv0[4], cv0[4];
#pragma unroll
        for (int r = 0; r < 4; ++r) {
            float gi = acc[0][r] + bi0, gf = acc[1][r] + bf0;
            float gg = acc[2][r] + bg0, go = acc[3][r] + bo0;
            float cn = sigmoidf_(gf) * cs0[r] + sigmoidf_(gi) * tanhf(gg);
            hv0[r] = sigmoidf_(go) * tanhf(cn);
            cv0[r] = cn;
        }
#pragma unroll
        for (int r = 0; r < 4; ++r) {
            int m = m0 + wave * 16 + lq * 4 + r;
            store_pair(h0, m, j, hv0[r], lane);
            if (t < T_STEPS - 1) {
                int tn = t + 1;
                bool msk = (reset_mask[m * T_STEPS + tn] | clear_mask[m * T_STEPS + tn]) != 0;
                float nv = noise[((size_t)(tn * 2) * BATCH + m) * HID + j] * noise_std[m * T_STEPS + tn];
                float hp = (msk ? 0.f : hv0[r]) + nv;
                cs0[r] = (msk ? 0.f : cv0[r]) + nv;
                store_pair(h0p + (size_t)(p ^ 1) * BH, m, j, hp, lane);
            } else {
                int idx = m * HID + j;
                out[THB + idx]          = hv0[r];
                out[THB + 2 * BH + idx] = cv0[r];
            }
        }
        sig_slot(&fY[((size_t)t * NMG + mg) * NJB + jb]);
        wait_slots(&fY[((size_t)t * NMG + mg) * NJB]);

        // ---- layer 1 GEMM: A = [h0 | h1prep[p]] (all agent loads) ----
#pragma unroll
        for (int g = 0; g < 4; ++g) acc[g] = (f32x4){0.f, 0.f, 0.f, 0.f};
#pragma unroll
        for (int k0 = 0; k0 < KDIM; k0 += BK) {
            {
                unsigned long long va[8];
#pragma unroll
                for (int i = 0; i < 8; ++i) {
                    int c = tid + i * 256;
                    int r = c >> 5;
                    int sc = (c & 31) * 4;
                    __hip_bfloat16* src = (k0 < HID)
                        ? (h0 + (size_t)(m0 + r) * HID + k0 + sc)
                        : (h1p + (size_t)p * BH + (size_t)(m0 + r) * HID + (k0 - HID) + sc);
                    va[i] = __hip_atomic_load((unsigned long long*)src,
                                              __ATOMIC_RELAXED, __HIP_MEMORY_SCOPE_AGENT);
                }
#pragma unroll
                for (int i = 0; i < 8; ++i) {
                    int c = tid + i * 256;
                    int r = c >> 5;
                    int sc = (c & 31) * 4;
                    *(unsigned long long*)&As[r * LDA + sc] = va[i];
                }
            }
#pragma unroll
            for (int i = 0; i < 4; ++i) {
                int c = tid + i * 256;
                int r = c >> 4;
                int kk = (c & 15) * 8;
                int grow = (r >> 4) * 512 + j0 + (r & 15);
                *(short8*)&Ws[r * LDA + kk] = *(const short8*)&((const short*)w1p)[(size_t)grow * KDIM + k0 + kk];
            }
            __syncthreads();
#pragma unroll
            for (int kk = 0; kk < BK; kk += 32) {
                short8 a = *(const short8*)&As[(wave * 16 + lr) * LDA + kk + lq * 8];
#pragma unroll
                for (int g = 0; g < 4; ++g) {
                    short8 w = *(const short8*)&Ws[(g * 16 + lr) * LDA + kk + lq * 8];
                    acc[g] = __builtin_amdgcn_mfma_f32_16x16x32_bf16(a, w, acc[g], 0, 0, 0);
                }
            }
            __syncthreads();
        }

        // ---- cell 1 + hidden out + t+1 layer-1 prep ----
#pragma unroll
        for (int r = 0; r < 4; ++r) {
            float gi = acc[0][r] + bi1, gf = acc[1][r] + bf1;
            float gg = acc[2][r] + bg1, go = acc[3][r] + bo1;
            float cn = sigmoidf_(gf) * cs1[r] + sigmoidf_(gi) * tanhf(gg);
            float hn = sigmoidf_(go) * tanhf(cn);
            int m   = m0 + wave * 16 + lq * 4 + r;
            int idx = m * HID + j;
            out[(size_t)t * BH + idx] = hn;
            if (t < T_STEPS - 1) {
                int tn = t + 1;
                bool msk = (reset_mask[m * T_STEPS + tn] | clear_mask[m * T_STEPS + tn]) != 0;
                float nv = noise[((size_t)(tn * 2 + 1) * BATCH + m) * HID + j] * noise_std[m * T_STEPS + tn];
                float hp = (msk ? 0.f : hn) + nv;
                cs1[r] = (msk ? 0.f : cn) + nv;
                store_pair(h1p + (size_t)(p ^ 1) * BH, m, j, hp, lane);
            } else {
                out[THB + BH + idx]     = hn;
                out[THB + 3 * BH + idx] = cn;
            }
        }
        if (t < T_STEPS - 1)
            sig_slot(&fX[((size_t)(t + 1) * NMG + mg) * NJB + jb]);
    }
}

extern "C" void kernel_launch(void* const* d_in, const int* in_sizes, int n_in,
                              void* d_out, int out_size, void* d_ws, size_t ws_size,
                              hipStream_t stream)
{
    const float* latent     = (const float*)d_in[0];
    const float* h_t        = (const float*)d_in[1];
    const float* c_t        = (const float*)d_in[2];
    const int*   reset_mask = (const int*)d_in[3];   // (1,B,T,1) flat b*T+t
    const int*   clear_mask = (const int*)d_in[4];   // (B,T)     flat b*T+t
    const float* noise_std  = (const float*)d_in[5]; // (B,T)     flat b*T+t
    const float* noise      = (const float*)d_in[6]; // (T,L,B,H)
    const float* wih0 = (const float*)d_in[7];
    const float* whh0 = (const float*)d_in[8];
    const float* bih0 = (const float*)d_in[9];
    const float* bhh0 = (const float*)d_in[10];
    const float* wih1 = (const float*)d_in[11];
    const float* whh1 = (const float*)d_in[12];
    const float* bih1 = (const float*)d_in[13];
    const float* bhh1 = (const float*)d_in[14];
    float* out = (float*)d_out;

    char* ws = (char*)d_ws;
    size_t off = 0;
    auto alloc = [&](size_t bytes) -> void* {
        void* p = ws + off;
        off += (bytes + 255) & ~(size_t)255;
        return p;
    };
    __hip_bfloat16* w0p = (__hip_bfloat16*)alloc((size_t)GATES * KDIM * 2);
    __hip_bfloat16* w1p = (__hip_bfloat16*)alloc((size_t)GATES * KDIM * 2);
    float* b0 = (float*)alloc(GATES * 4);
    float* b1 = (float*)alloc(GATES * 4);
    __hip_bfloat16* h0p = (__hip_bfloat16*)alloc((size_t)2 * BH * 2);
    __hip_bfloat16* h1p = (__hip_bfloat16*)alloc((size_t)2 * BH * 2);
    __hip_bfloat16* h0  = (__hip_bfloat16*)alloc((size_t)BH * 2);
    size_t flag_bytes = (size_t)2 * T_STEPS * NMG * NJB * sizeof(unsigned);
    unsigned* flags = (unsigned*)alloc(flag_bytes);

    hipMemsetAsync(flags, 0, flag_bytes, stream);

    pack_weights<<<(GATES * KDIM) / 256, 256, 0, stream>>>(
        wih0, whh0, wih1, whh1, bih0, bhh0, bih1, bhh1, w0p, w1p, b0, b1);

    lstm_scan<<<NMG * NJB, 256, 0, stream>>>(
        latent, h_t, c_t, reset_mask, clear_mask, noise_std, noise,
        w0p, w1p, b0, b1, h0p, h1p, h0, flags, out);
}